// Round 15
// baseline (508.809 us; speedup 1.0000x reference)
//
#include <hip/hip_runtime.h>
#include <stdint.h>

#define MAX_DEG   10
#define DEG_COUNT 30000
#define N_ATOMS   330000      // 11 * 30000
#define NF        128
#define BATCH     128
#define SORT_BLOCKS 256
#define SORT_CHUNK  1290      // ceil(330000/256)
#define NB_BUILD  1408        // 11*128*256/256
#define NB_CAST   41250       // N_ATOMS*128/4/256
#define NSLICES   8           // mreduce slices per molecule

typedef __attribute__((ext_vector_type(8))) short bf16x8;   // 8 bf16 (4 VGPRs)
typedef __attribute__((ext_vector_type(4))) float f32x4;
typedef __attribute__((ext_vector_type(2))) float f32x2;

__device__ __forceinline__ float bf2f(unsigned short h) {
  union { unsigned u; float f; } v; v.u = ((unsigned)h) << 16; return v.f;
}
__device__ __forceinline__ unsigned short f2bf(float f) {
  union { float f; unsigned u; } v; v.f = f;
  unsigned u = v.u;
  unsigned r = (u + 0x7fffu + ((u >> 16) & 1u)) >> 16;   // RNE
  return (unsigned short)r;
}

struct AdjPtrs { const int* p[10]; };

#define NEG_INF_BITS 0xFF800000

// ---------------------------------------------------------------------------
// K_prep: block-range dispatch — three independent jobs, one launch, each at
// its natural parallelism.
// ---------------------------------------------------------------------------
__global__ __launch_bounds__(256) void k_prep(
    const float* __restrict__ W,
    const float* __restrict__ b,
    const f32x4* __restrict__ atoms4,
    const int* __restrict__ membership,
    unsigned short* __restrict__ BcatT,     // [11][128][256]
    float* __restrict__ biascat,            // [11][128]
    ushort4* __restrict__ dst4,             // bf16 atoms copy
    int* __restrict__ blockHistT)           // [128 m][256 b]
{
  const int bx = blockIdx.x;
  const int tid = threadIdx.x;
  __shared__ int bins[BATCH];

  if (bx < NB_BUILD) {
    int idx = bx * 256 + tid;
    if (idx < 11 * 128) {           // bias: [d][n]
      int d = idx >> 7, n = idx & 127;
      float f = (d >= 1) ? (b[(2 * (d - 1)) * 128 + n] + b[(2 * d - 1) * 128 + n])
                         : b[20 * 128 + n];
      biascat[idx] = f;
    }
    if (idx < 11 * 128 * 256) {
      int d = idx >> 15;
      int rem = idx & 32767;
      int n = rem >> 8;
      int k = rem & 255;
      float v;
      if (k < 128) {
        v = (d >= 1) ? W[(2 * (d - 1)) * 16384 + k * 128 + n] : 0.f;
      } else {
        int ks = k - 128;
        int wi = (d >= 1) ? (2 * d - 1) : 20;
        v = W[wi * 16384 + ks * 128 + n];
      }
      BcatT[idx] = f2bf(v);   // idx == d*32768 + n*256 + k
    }
  } else if (bx < NB_BUILD + NB_CAST) {
    size_t i = (size_t)(bx - NB_BUILD) * 256 + tid;   // one float4 -> ushort4
    f32x4 v = __builtin_nontemporal_load(atoms4 + i);
    ushort4 o;
    o.x = f2bf(v[0]); o.y = f2bf(v[1]); o.z = f2bf(v[2]); o.w = f2bf(v[3]);
    dst4[i] = o;
  } else {
    int bh = bx - NB_BUILD - NB_CAST;     // 0..SORT_BLOCKS-1
    if (tid < BATCH) bins[tid] = 0;
    __syncthreads();
    int lo = bh * SORT_CHUNK, hi = min(lo + SORT_CHUNK, N_ATOMS);
    for (int i = lo + tid; i < hi; i += 256)
      atomicAdd(&bins[membership[i]], 1);
    __syncthreads();
    if (tid < BATCH) blockHistT[tid * 256 + bh] = bins[tid];
  }
}

// ---------------------------------------------------------------------------
// K_scan: parallel scan. 128 blocks (one per molecule) x 256 threads.
// ---------------------------------------------------------------------------
__global__ __launch_bounds__(256) void k_scan(
    const int* __restrict__ blockHistT,     // [128 m][256 b]
    int* __restrict__ relOffT,              // [128 m][256 b] exclusive
    int* __restrict__ tot)                  // [128]
{
  const int m = blockIdx.x;
  const int tid = threadIdx.x;              // = b
  __shared__ int ws[4];
  int v = blockHistT[m * 256 + tid];
  int x = v;
#pragma unroll
  for (int o = 1; o < 64; o <<= 1) {
    int t = __shfl_up(x, o, 64);
    if ((tid & 63) >= o) x += t;
  }
  if ((tid & 63) == 63) ws[tid >> 6] = x;
  __syncthreads();
  int wb = 0;
  for (int w = 0; w < (tid >> 6); ++w) wb += ws[w];
  int incl = wb + x;
  relOffT[m * 256 + tid] = incl - v;
  if (tid == 255) tot[m] = incl;
}

// K_scatter: seed LDS bins with base[m] + this chunk's offsets, then
// block-local native int LDS atomics + plain 4B writes.
__global__ __launch_bounds__(256) void k_scatter(
    const int* __restrict__ membership,
    const int* __restrict__ relOffT,
    const int* __restrict__ tot,
    int* __restrict__ perm)
{
  __shared__ int totS[BATCH], baseS[BATCH], bins[BATCH];
  const int tid = threadIdx.x;
  if (tid < BATCH) totS[tid] = tot[tid];
  __syncthreads();
  if (tid == 0) {
    int a = 0;
    for (int i = 0; i < BATCH; ++i) { baseS[i] = a; a += totS[i]; }
  }
  __syncthreads();
  if (tid < BATCH) bins[tid] = baseS[tid] + relOffT[tid * 256 + blockIdx.x];
  __syncthreads();
  int lo = blockIdx.x * SORT_CHUNK, hi = min(lo + SORT_CHUNK, N_ATOMS);
  for (int i = lo + tid; i < hi; i += 256) {
    int m = membership[i];
    int pos = atomicAdd(&bins[m], 1);   // native int LDS atomic
    perm[pos] = i;
  }
}

// ---------------------------------------------------------------------------
// Phase-0 helper (fused nsum): one wave computes 16 nsum rows of its block
// into LDS, 2 rows/iter. Bit-identical accumulation to the old k_nsum.
// ---------------------------------------------------------------------------
template<int D>
__device__ __forceinline__ void nsum_phase0(const unsigned* __restrict__ atomsU,
                                            const int* __restrict__ abase,
                                            unsigned* __restrict__ NS,
                                            int rowTile, int wave, int lane) {
  for (int it = 0; it < 8; ++it) {
    int iloc = wave * 16 + it * 2;               // local row 0..127
    int r0 = rowTile * 128 + iloc;
    int sw0 = lane ^ ((iloc & 7) << 2);
    int sw1 = lane ^ (((iloc + 1) & 7) << 2);
    if (r0 < DEG_COUNT - 1) {                    // normal pair (r0, r0+1)
      const int* a = abase + (size_t)r0 * D;
      int myIdx = (lane < 2 * D) ? a[lane] : 0;
      unsigned xs[2 * D];
#pragma unroll
      for (int j = 0; j < 2 * D; ++j) {
        int nbr = __shfl(myIdx, j, 64);
        xs[j] = atomsU[(size_t)nbr * 64 + lane];
      }
      float s0a = 0.f, s1a = 0.f, s0b = 0.f, s1b = 0.f;
#pragma unroll
      for (int j = 0; j < D; ++j) {
        s0a += bf2f((unsigned short)(xs[j] & 0xffff));
        s1a += bf2f((unsigned short)(xs[j] >> 16));
      }
#pragma unroll
      for (int j = D; j < 2 * D; ++j) {
        s0b += bf2f((unsigned short)(xs[j] & 0xffff));
        s1b += bf2f((unsigned short)(xs[j] >> 16));
      }
      NS[(size_t)iloc * 64 + sw0]       = (unsigned)f2bf(s0a) | ((unsigned)f2bf(s1a) << 16);
      NS[(size_t)(iloc + 1) * 64 + sw1] = (unsigned)f2bf(s0b) | ((unsigned)f2bf(s1b) << 16);
    } else {                                     // tail: both rows clamp to 29999
      const int* a = abase + (size_t)(DEG_COUNT - 1) * D;
      int myIdx = (lane < D) ? a[lane] : 0;
      unsigned xs[D];
#pragma unroll
      for (int j = 0; j < D; ++j) {
        int nbr = __shfl(myIdx, j, 64);
        xs[j] = atomsU[(size_t)nbr * 64 + lane];
      }
      float s0 = 0.f, s1 = 0.f;
#pragma unroll
      for (int j = 0; j < D; ++j) {
        s0 += bf2f((unsigned short)(xs[j] & 0xffff));
        s1 += bf2f((unsigned short)(xs[j] >> 16));
      }
      unsigned p = (unsigned)f2bf(s0) | ((unsigned)f2bf(s1) << 16);
      NS[(size_t)iloc * 64 + sw0] = p;
      NS[(size_t)(iloc + 1) * 64 + sw1] = p;
    }
  }
}

// ---------------------------------------------------------------------------
// K3: fused nsum + streaming MFMA GEMM — activated half (128 cols).
// NEW: split-K B staging — only 32 KB LDS live at any time (NS table and
// each 128-wide B half are both exactly 32 KB, used sequentially) ->
// 4 blocks/CU (was 2 at 64 KB), doubling TLP for the latency-bound
// phase-0 gather. Per-acc accumulation stays ks 0..7 ascending =>
// bit-identical output.
// ---------------------------------------------------------------------------
__global__ __launch_bounds__(512, 4) void k_gemm(
    const unsigned short* __restrict__ atomsBf,
    AdjPtrs adj,
    const unsigned short* __restrict__ BcatT,    // [11][128][256] n-major
    const float* __restrict__ biascat,           // [11][128]
    const float* __restrict__ gamma,
    const float* __restrict__ beta,
    float* __restrict__ out0)                    // xn FINAL (fp32)
{
  const int d = blockIdx.y;
  const int rowTile = blockIdx.x;
  const int tid = threadIdx.x;
  const int lane = tid & 63;
  const int wave = tid >> 6;          // 0..7
  const int m16 = lane & 15;
  const int g = lane >> 4;            // k-group 0..3

  __shared__ unsigned short Bs[128 * 128];   // 32 KiB: NS, then B half 0, then B half 1
  unsigned* NS = (unsigned*)Bs;              // [128 rows][64 words], swizzled

  const unsigned short* Bd = BcatT + d * 32768;
  const unsigned* atomsU = (const unsigned*)atomsBf;

  // ---- self A-frags (ks 4-7) from global first (overlap with phase 0) ----
  const int rowBase = rowTile * 128 + wave * 16;
  bf16x8 af[8];
  {
    int rbL = rowBase + m16; if (rbL > DEG_COUNT - 1) rbL = DEG_COUNT - 1;
    size_t gr = (size_t)d * DEG_COUNT + rbL;
#pragma unroll
    for (int ks = 4; ks < 8; ++ks)
      af[ks] = *(const bf16x8*)(atomsBf + gr * 128 + (ks - 4) * 32 + g * 8);
  }

  // ---- phase 0: fused nsum into LDS; af ks0-3 from LDS ----
  if (d > 0) {
    const int* abase = adj.p[d - 1];
    switch (d) {
      case 1:  nsum_phase0<1>(atomsU, abase, NS, rowTile, wave, lane); break;
      case 2:  nsum_phase0<2>(atomsU, abase, NS, rowTile, wave, lane); break;
      case 3:  nsum_phase0<3>(atomsU, abase, NS, rowTile, wave, lane); break;
      case 4:  nsum_phase0<4>(atomsU, abase, NS, rowTile, wave, lane); break;
      case 5:  nsum_phase0<5>(atomsU, abase, NS, rowTile, wave, lane); break;
      case 6:  nsum_phase0<6>(atomsU, abase, NS, rowTile, wave, lane); break;
      case 7:  nsum_phase0<7>(atomsU, abase, NS, rowTile, wave, lane); break;
      case 8:  nsum_phase0<8>(atomsU, abase, NS, rowTile, wave, lane); break;
      case 9:  nsum_phase0<9>(atomsU, abase, NS, rowTile, wave, lane); break;
      default: nsum_phase0<10>(atomsU, abase, NS, rowTile, wave, lane); break;
    }
    __syncthreads();
    const char* nsb = (const char*)NS;
    const int rowb = (wave * 16 + m16) * 256;         // byte base, local row
    const int sw = (m16 & 7) << 4;
#pragma unroll
    for (int ks = 0; ks < 4; ++ks)
      af[ks] = *(const bf16x8*)(nsb + ((rowb + ks * 64 + g * 16) ^ sw));
  } else {
    bf16x8 z = {0, 0, 0, 0, 0, 0, 0, 0};
#pragma unroll
    for (int ks = 0; ks < 4; ++ks) af[ks] = z;
  }

  f32x4 acc[8];
#pragma unroll
  for (int ct = 0; ct < 8; ++ct) acc[ct] = (f32x4){0.f, 0.f, 0.f, 0.f};

  const int ldsMask = (m16 & 7) << 4;

#pragma unroll
  for (int h = 0; h < 2; ++h) {
    __syncthreads();   // NS consumed (h=0) / previous B half consumed (h=1)
    // stage B half h: 128 n-rows x 128 k (32 KB), swizzled rows of 256B
#pragma unroll
    for (int it = 0; it < 4; ++it) {
      int flat = it * 512 + tid;        // 16B chunks; 16 chunks per row
      int row = flat >> 4;              // 0..127
      int c = flat & 15;
      uint4 v = *(const uint4*)(Bd + row * 256 + h * 128 + c * 8);
      int kb = (c * 16) ^ ((row & 7) << 4);
      *(uint4*)((char*)Bs + row * 256 + kb) = v;
    }
    __syncthreads();
#pragma unroll
    for (int ct = 0; ct < 8; ++ct) {
      const char* bbase = (const char*)Bs + (ct * 16 + m16) * 256;
      bf16x8 bf[4];
#pragma unroll
      for (int ks = 0; ks < 4; ++ks)
        bf[ks] = *(const bf16x8*)(bbase + ((ks * 64 + g * 16) ^ ldsMask));
#pragma unroll
      for (int ks = 0; ks < 4; ++ks)
        acc[ct] = __builtin_amdgcn_mfma_f32_16x16x32_bf16(af[h * 4 + ks], bf[ks], acc[ct], 0, 0, 0);
    }
  }

  // ---- epilogue: bias, LN over 128 cols, coalesced stores ----
  float bias_[8], gam[8], bet[8];
#pragma unroll
  for (int ct = 0; ct < 8; ++ct) {
    bias_[ct] = biascat[d * 128 + ct * 16 + m16];
    gam[ct] = gamma[ct * 16 + m16];
    bet[ct] = beta[ct * 16 + m16];
  }

#pragma unroll
  for (int ct = 0; ct < 8; ++ct)
#pragma unroll
    for (int r = 0; r < 4; ++r) acc[ct][r] += bias_[ct];

  float s[4], qq[4];
#pragma unroll
  for (int r = 0; r < 4; ++r) {
    s[r] = 0.f; qq[r] = 0.f;
#pragma unroll
    for (int ct = 0; ct < 8; ++ct) {
      float v = acc[ct][r];
      s[r] += v; qq[r] += v * v;
    }
  }
#pragma unroll
  for (int off = 8; off >= 1; off >>= 1) {
#pragma unroll
    for (int r = 0; r < 4; ++r) {
      s[r]  += __shfl_xor(s[r],  off, 64);
      qq[r] += __shfl_xor(qq[r], off, 64);
    }
  }

#pragma unroll
  for (int r = 0; r < 4; ++r) {
    int rb = rowBase + g * 4 + r;
    float mean = s[r] * (1.0f / 128.0f);
    float var  = qq[r] * (1.0f / 128.0f) - mean * mean;
    float inv  = 1.0f / (sqrtf(var + 1e-5f) + 1e-5f);   // ref: sqrt(var+eps)+eps
    if (rb < DEG_COUNT) {
      size_t grow = (size_t)d * DEG_COUNT + rb;
#pragma unroll
      for (int ct = 0; ct < 8; ++ct)
        out0[grow * 128 + ct * 16 + m16] = gam[ct] * ((acc[ct][r] - mean) * inv) + bet[ct];
    }
  }
}

// ---------------------------------------------------------------------------
// K_mreduce: ONE perm pass doing BOTH segment-max(xn) AND per-(molecule,
// degree) atom sums + counts. Per-wave LDS tables with PLAIN adds. Now
// NSLICES=8 (1024 blocks) for more TLP.
// ---------------------------------------------------------------------------
__global__ __launch_bounds__(512) void k_mreduce(
    const f32x2* __restrict__ xnV,          // out0 as f32x2
    const unsigned* __restrict__ atomsU,
    const int* __restrict__ perm,
    const int* __restrict__ tot,            // [128]
    float* __restrict__ Spart,      // [NSLICES][128][11][128]
    int* __restrict__ cntPart,      // [NSLICES][128][11]
    float2* __restrict__ pmax4)     // [NSLICES][128][64] float2
{
  const int m = blockIdx.x >> 3;
  const int s = blockIdx.x & 7;
  const int wave = threadIdx.x >> 6, lane = threadIdx.x & 63;

  __shared__ float S[8][11][128];   // physical col p: p<64 -> col 2p, else 2(p-64)+1
  __shared__ int C[8][11];
  __shared__ float2 maxT[8][64];
  __shared__ int totS[BATCH];
  __shared__ int rangeS[2];
  for (int e = lane; e < 11 * 128; e += 64) S[wave][e >> 7][e & 127] = 0.f;
  if (lane < 11) C[wave][lane] = 0;
  if (threadIdx.x < BATCH) totS[threadIdx.x] = tot[threadIdx.x];
  __syncthreads();
  if (threadIdx.x == 0) {
    int a = 0;
    for (int i = 0; i < m; ++i) a += totS[i];
    rangeS[0] = a; rangeS[1] = totS[m];
  }
  __syncthreads();
  const int b0 = rangeS[0], cnt = rangeS[1];
  const int lo = b0 + (cnt * s) / NSLICES;
  const int hi = b0 + (cnt * (s + 1)) / NSLICES;

  const float NEG_INF = __int_as_float((int)NEG_INF_BITS);
  float mx0 = NEG_INF, mx1 = NEG_INF;

  for (int i = lo + wave * 2; i < hi; i += 16) {
    int r0 = perm[i];
    bool has1 = (i + 1 < hi);
    int r1 = has1 ? perm[i + 1] : r0;
    f32x2 x0 = __builtin_nontemporal_load(xnV + (size_t)r0 * 64 + lane);
    unsigned a0 = __builtin_nontemporal_load(atomsU + (size_t)r0 * 64 + lane);
    f32x2 x1 = __builtin_nontemporal_load(xnV + (size_t)r1 * 64 + lane);
    unsigned a1 = __builtin_nontemporal_load(atomsU + (size_t)r1 * 64 + lane);
    int d0 = r0 / DEG_COUNT;                    // wave-uniform
    mx0 = fmaxf(mx0, x0[0]);
    mx1 = fmaxf(mx1, x0[1]);
    S[wave][d0][lane]      += bf2f((unsigned short)(a0 & 0xffff));   // plain LDS add
    S[wave][d0][64 + lane] += bf2f((unsigned short)(a0 >> 16));
    if (lane == 0) C[wave][d0]++;
    if (has1) {
      int d1 = r1 / DEG_COUNT;
      mx0 = fmaxf(mx0, x1[0]);
      mx1 = fmaxf(mx1, x1[1]);
      S[wave][d1][lane]      += bf2f((unsigned short)(a1 & 0xffff));
      S[wave][d1][64 + lane] += bf2f((unsigned short)(a1 >> 16));
      if (lane == 0) C[wave][d1]++;
    }
  }
  maxT[wave][lane] = make_float2(mx0, mx1);
  __syncthreads();

  if (threadIdx.x < 64) {
    int l = threadIdx.x;
    float2 mm = maxT[0][l];
#pragma unroll
    for (int w = 1; w < 8; ++w) {
      float2 b = maxT[w][l]; mm.x = fmaxf(mm.x, b.x); mm.y = fmaxf(mm.y, b.y);
    }
    pmax4[((size_t)s * 128 + m) * 64 + l] = mm;
  }
  for (int e = threadIdx.x; e < 11 * 128; e += 512) {
    int d = e >> 7, p = e & 127;
    float t = 0.f;
#pragma unroll
    for (int w = 0; w < 8; ++w) t += S[w][d][p];
    int col = (p < 64) ? (2 * p) : (2 * (p - 64) + 1);   // de-permute
    Spart[(((size_t)s * 128 + m) * 11 + d) * 128 + col] = t;
  }
  if (threadIdx.x < 11) {
    int t = 0;
#pragma unroll
    for (int w = 0; w < 8; ++w) t += C[w][threadIdx.x];
    cntPart[((size_t)s * 128 + m) * 11 + threadIdx.x] = t;
  }
}

// ---------------------------------------------------------------------------
// K_ynfinal: yn = LN( sum_d S[m,d] @ Wg_d + cnt[m,d]*bg_d ) -> out1, and
// merge NSLICES max slices -> out2. 128 blocks x 128 threads.
// ---------------------------------------------------------------------------
__global__ __launch_bounds__(128) void k_ynfinal(
    const float* __restrict__ Spart,
    const int* __restrict__ cntPart,
    const float* __restrict__ W,
    const float* __restrict__ b,
    const float* __restrict__ gamma,
    const float* __restrict__ beta,
    const float* __restrict__ pmax4,        // [NSLICES][128][128]
    float* __restrict__ out1,
    float* __restrict__ out2)
{
  int m = blockIdx.x;
  int j = threadIdx.x;

  float g = __int_as_float((int)NEG_INF_BITS);
#pragma unroll
  for (int sl = 0; sl < NSLICES; ++sl)
    g = fmaxf(g, pmax4[((size_t)sl * 128 + m) * 128 + j]);
  out2[m * 128 + j] = g;

  __shared__ float Sm[11][128];
  __shared__ float cw[11];
  for (int e = j; e < 11 * 128; e += 128) {
    int d = e >> 7, c = e & 127;
    float t = 0.f;
#pragma unroll
    for (int sl = 0; sl < NSLICES; ++sl)
      t += Spart[(((size_t)sl * 128 + m) * 11 + d) * 128 + c];
    Sm[d][c] = t;
  }
  if (j < 11) {
    int t = 0;
#pragma unroll
    for (int sl = 0; sl < NSLICES; ++sl)
      t += cntPart[((size_t)sl * 128 + m) * 11 + j];
    cw[j] = (float)t;
  }
  __syncthreads();

  float acc = 0.f;
  for (int d = 0; d < 11; ++d) {
    int wi = (d >= 1) ? (20 + d) : 31;
    const float* Wd = W + wi * 16384;
    float a0 = 0.f, a1 = 0.f, a2 = 0.f, a3 = 0.f;
    for (int k = 0; k < 128; k += 4) {
      a0 += Sm[d][k]     * Wd[k * 128 + j];
      a1 += Sm[d][k + 1] * Wd[(k + 1) * 128 + j];
      a2 += Sm[d][k + 2] * Wd[(k + 2) * 128 + j];
      a3 += Sm[d][k + 3] * Wd[(k + 3) * 128 + j];
    }
    acc += (a0 + a1) + (a2 + a3);
    acc += cw[d] * b[wi * 128 + j];
  }

  float ws_ = acc, wq = acc * acc;
#pragma unroll
  for (int off = 32; off >= 1; off >>= 1) {
    ws_ += __shfl_xor(ws_, off, 64);
    wq  += __shfl_xor(wq, off, 64);
  }
  __shared__ float red[4];
  int wave = j >> 6, lane = j & 63;
  if (lane == 0) { red[wave * 2] = ws_; red[wave * 2 + 1] = wq; }
  __syncthreads();
  float Ssum = red[0] + red[2], Q = red[1] + red[3];
  float mean = Ssum * (1.f / 128.f);
  float var = Q * (1.f / 128.f) - mean * mean;
  float inv = 1.f / (sqrtf(var + 1e-5f) + 1e-5f);
  out1[m * 128 + j] = gamma[j] * ((acc - mean) * inv) + beta[j];
}

// ---------------------------------------------------------------------------
extern "C" void kernel_launch(void* const* d_in, const int* in_sizes, int n_in,
                              void* d_out, int out_size, void* d_ws, size_t ws_size,
                              hipStream_t stream) {
  const float* atoms = (const float*)d_in[0];
  // d_in[1] = deg_slice (unused; buckets are static)
  const int* membership = (const int*)d_in[2];
  AdjPtrs adj;
  for (int i = 0; i < 10; ++i) adj.p[i] = (const int*)d_in[3 + i];
  const float* W     = (const float*)d_in[13];
  const float* b     = (const float*)d_in[14];
  const float* gamma = (const float*)d_in[15];
  const float* beta  = (const float*)d_in[16];

  char* ws = (char*)d_ws;
  size_t off = 0;
  unsigned short* atomsBf = (unsigned short*)(ws + off); off += (size_t)N_ATOMS * 128 * 2;
  unsigned short* BcatT   = (unsigned short*)(ws + off); off += (size_t)11 * 128 * 256 * 2;
  float* biascat          = (float*)(ws + off);          off += (size_t)11 * 128 * 4;
  int* perm               = (int*)(ws + off);            off += (size_t)N_ATOMS * 4;
  int* tot                = (int*)(ws + off);            off += 512;
  int* blockHistT         = (int*)(ws + off);            off += (size_t)BATCH * SORT_BLOCKS * 4;
  int* relOffT            = (int*)(ws + off);            off += (size_t)BATCH * SORT_BLOCKS * 4;
  float* Spart            = (float*)(ws + off);          off += (size_t)NSLICES * 128 * 11 * 128 * 4;
  int* cntPart            = (int*)(ws + off);            off += (size_t)NSLICES * 128 * 11 * 4;
  float* pmax4            = (float*)(ws + off);          off += (size_t)NSLICES * 128 * 128 * 4;

  float* out0 = (float*)d_out;
  float* out1 = out0 + (size_t)N_ATOMS * 128;
  float* out2 = out1 + 16384;

  // 1) build B/bias + cast + histogram (block-range dispatch, one launch)
  hipLaunchKernelGGL(k_prep, dim3(NB_BUILD + NB_CAST + SORT_BLOCKS), dim3(256), 0, stream,
                     W, b, (const f32x4*)atoms, membership,
                     BcatT, biascat, (ushort4*)atomsBf, blockHistT);
  // 2) parallel scan -> relOffT + tot
  hipLaunchKernelGGL(k_scan, dim3(128), dim3(256), 0, stream, blockHistT, relOffT, tot);
  // 3) scatter -> perm
  hipLaunchKernelGGL(k_scatter, dim3(SORT_BLOCKS), dim3(256), 0, stream,
                     membership, relOffT, tot, perm);
  // 4) fused nsum + activated GEMM + LN (split-K, 32KB LDS -> 4 blocks/CU)
  hipLaunchKernelGGL(k_gemm, dim3(236, 11), dim3(512), 0, stream,
                     atomsBf, adj, BcatT, biascat, gamma, beta, out0);
  // 5) fused segment-max(xn) + per-(mol,deg) atom sums (single perm pass)
  hipLaunchKernelGGL(k_mreduce, dim3(128 * NSLICES), dim3(512), 0, stream,
                     (const f32x2*)out0, (const unsigned*)atomsBf, perm, tot,
                     Spart, cntPart, (float2*)pmax4);
  // 6) yn (algebraic gathered path) + max merge
  hipLaunchKernelGGL(k_ynfinal, dim3(128), dim3(128), 0, stream,
                     Spart, cntPart, W, b, gamma, beta, pmax4, out1, out2);
}

// Round 16
// 492.500 us; speedup vs baseline: 1.0331x; 1.0331x over previous
//
#include <hip/hip_runtime.h>
#include <stdint.h>

#define MAX_DEG   10
#define DEG_COUNT 30000
#define N_ATOMS   330000      // 11 * 30000
#define NF        128
#define BATCH     128
#define SORT_BLOCKS 256
#define SORT_CHUNK  1290      // ceil(330000/256)
#define NB_BUILD  1408        // 11*128*256/256
#define NB_CAST   41250       // N_ATOMS*128/4/256
#define NSLICES   4           // mreduce slices per molecule (8 regressed, r15)

typedef __attribute__((ext_vector_type(8))) short bf16x8;   // 8 bf16 (4 VGPRs)
typedef __attribute__((ext_vector_type(4))) float f32x4;
typedef __attribute__((ext_vector_type(2))) float f32x2;

__device__ __forceinline__ float bf2f(unsigned short h) {
  union { unsigned u; float f; } v; v.u = ((unsigned)h) << 16; return v.f;
}
__device__ __forceinline__ unsigned short f2bf(float f) {
  union { float f; unsigned u; } v; v.f = f;
  unsigned u = v.u;
  unsigned r = (u + 0x7fffu + ((u >> 16) & 1u)) >> 16;   // RNE
  return (unsigned short)r;
}

struct AdjPtrs { const int* p[10]; };

#define NEG_INF_BITS 0xFF800000

// ---------------------------------------------------------------------------
// K_prep: block-range dispatch — three independent jobs, one launch, each at
// its natural parallelism.
// ---------------------------------------------------------------------------
__global__ __launch_bounds__(256) void k_prep(
    const float* __restrict__ W,
    const float* __restrict__ b,
    const f32x4* __restrict__ atoms4,
    const int* __restrict__ membership,
    unsigned short* __restrict__ BcatT,     // [11][128][256]
    float* __restrict__ biascat,            // [11][128]
    ushort4* __restrict__ dst4,             // bf16 atoms copy
    int* __restrict__ blockHistT)           // [128 m][256 b]
{
  const int bx = blockIdx.x;
  const int tid = threadIdx.x;
  __shared__ int bins[BATCH];

  if (bx < NB_BUILD) {
    int idx = bx * 256 + tid;
    if (idx < 11 * 128) {           // bias: [d][n]
      int d = idx >> 7, n = idx & 127;
      float f = (d >= 1) ? (b[(2 * (d - 1)) * 128 + n] + b[(2 * d - 1) * 128 + n])
                         : b[20 * 128 + n];
      biascat[idx] = f;
    }
    if (idx < 11 * 128 * 256) {
      int d = idx >> 15;
      int rem = idx & 32767;
      int n = rem >> 8;
      int k = rem & 255;
      float v;
      if (k < 128) {
        v = (d >= 1) ? W[(2 * (d - 1)) * 16384 + k * 128 + n] : 0.f;
      } else {
        int ks = k - 128;
        int wi = (d >= 1) ? (2 * d - 1) : 20;
        v = W[wi * 16384 + ks * 128 + n];
      }
      BcatT[idx] = f2bf(v);   // idx == d*32768 + n*256 + k
    }
  } else if (bx < NB_BUILD + NB_CAST) {
    size_t i = (size_t)(bx - NB_BUILD) * 256 + tid;   // one float4 -> ushort4
    f32x4 v = __builtin_nontemporal_load(atoms4 + i);
    ushort4 o;
    o.x = f2bf(v[0]); o.y = f2bf(v[1]); o.z = f2bf(v[2]); o.w = f2bf(v[3]);
    dst4[i] = o;
  } else {
    int bh = bx - NB_BUILD - NB_CAST;     // 0..SORT_BLOCKS-1
    if (tid < BATCH) bins[tid] = 0;
    __syncthreads();
    int lo = bh * SORT_CHUNK, hi = min(lo + SORT_CHUNK, N_ATOMS);
    for (int i = lo + tid; i < hi; i += 256)
      atomicAdd(&bins[membership[i]], 1);
    __syncthreads();
    if (tid < BATCH) blockHistT[tid * 256 + bh] = bins[tid];
  }
}

// ---------------------------------------------------------------------------
// K_scan: parallel scan. 128 blocks (one per molecule) x 256 threads.
// ---------------------------------------------------------------------------
__global__ __launch_bounds__(256) void k_scan(
    const int* __restrict__ blockHistT,     // [128 m][256 b]
    int* __restrict__ relOffT,              // [128 m][256 b] exclusive
    int* __restrict__ tot)                  // [128]
{
  const int m = blockIdx.x;
  const int tid = threadIdx.x;              // = b
  __shared__ int ws[4];
  int v = blockHistT[m * 256 + tid];
  int x = v;
#pragma unroll
  for (int o = 1; o < 64; o <<= 1) {
    int t = __shfl_up(x, o, 64);
    if ((tid & 63) >= o) x += t;
  }
  if ((tid & 63) == 63) ws[tid >> 6] = x;
  __syncthreads();
  int wb = 0;
  for (int w = 0; w < (tid >> 6); ++w) wb += ws[w];
  int incl = wb + x;
  relOffT[m * 256 + tid] = incl - v;
  if (tid == 255) tot[m] = incl;
}

// K_scatter: seed LDS bins with base[m] + this chunk's offsets, then
// block-local native int LDS atomics + plain 4B writes.
__global__ __launch_bounds__(256) void k_scatter(
    const int* __restrict__ membership,
    const int* __restrict__ relOffT,
    const int* __restrict__ tot,
    int* __restrict__ perm)
{
  __shared__ int totS[BATCH], baseS[BATCH], bins[BATCH];
  const int tid = threadIdx.x;
  if (tid < BATCH) totS[tid] = tot[tid];
  __syncthreads();
  if (tid == 0) {
    int a = 0;
    for (int i = 0; i < BATCH; ++i) { baseS[i] = a; a += totS[i]; }
  }
  __syncthreads();
  if (tid < BATCH) bins[tid] = baseS[tid] + relOffT[tid * 256 + blockIdx.x];
  __syncthreads();
  int lo = blockIdx.x * SORT_CHUNK, hi = min(lo + SORT_CHUNK, N_ATOMS);
  for (int i = lo + tid; i < hi; i += 256) {
    int m = membership[i];
    int pos = atomicAdd(&bins[m], 1);   // native int LDS atomic
    perm[pos] = i;
  }
}

// ---------------------------------------------------------------------------
// Phase-0 helper (fused nsum): one wave computes 16 nsum rows of its block
// into LDS. NEW: 4 rows/iter fast path (4D <= 40 independent gathers in
// flight per wave — the one untested gather lever after occupancy/LDS were
// falsified in r15). Accumulation stays j-ascending per row => bit-identical.
// Tail rowTile falls back to per-row clamped path (same clamp semantics).
// ---------------------------------------------------------------------------
template<int D>
__device__ __forceinline__ void nsum_row1(const unsigned* __restrict__ atomsU,
                                          const int* __restrict__ abase,
                                          unsigned* __restrict__ NS,
                                          int iloc, int rclamp, int lane) {
  const int* a = abase + (size_t)rclamp * D;
  int myIdx = (lane < D) ? a[lane] : 0;
  unsigned xs[D];
#pragma unroll
  for (int j = 0; j < D; ++j) {
    int nbr = __shfl(myIdx, j, 64);
    xs[j] = atomsU[(size_t)nbr * 64 + lane];
  }
  float s0 = 0.f, s1 = 0.f;
#pragma unroll
  for (int j = 0; j < D; ++j) {
    s0 += bf2f((unsigned short)(xs[j] & 0xffff));
    s1 += bf2f((unsigned short)(xs[j] >> 16));
  }
  int sw = lane ^ ((iloc & 7) << 2);
  NS[(size_t)iloc * 64 + sw] = (unsigned)f2bf(s0) | ((unsigned)f2bf(s1) << 16);
}

template<int D>
__device__ __forceinline__ void nsum_phase0(const unsigned* __restrict__ atomsU,
                                            const int* __restrict__ abase,
                                            unsigned* __restrict__ NS,
                                            int rowTile, int wave, int lane) {
  for (int it = 0; it < 4; ++it) {
    int iloc = wave * 16 + it * 4;               // local row 0..127, 4 rows
    int r0 = rowTile * 128 + iloc;
    if (r0 + 3 < DEG_COUNT) {                    // fast path: rows r0..r0+3
      const int* a = abase + (size_t)r0 * D;
      int myIdx = (lane < 4 * D) ? a[lane] : 0;
      unsigned xs[4 * D];
#pragma unroll
      for (int j = 0; j < 4 * D; ++j) {
        int nbr = __shfl(myIdx, j, 64);
        xs[j] = atomsU[(size_t)nbr * 64 + lane];
      }
#pragma unroll
      for (int rr = 0; rr < 4; ++rr) {
        float s0 = 0.f, s1 = 0.f;
#pragma unroll
        for (int j = rr * D; j < (rr + 1) * D; ++j) {
          s0 += bf2f((unsigned short)(xs[j] & 0xffff));
          s1 += bf2f((unsigned short)(xs[j] >> 16));
        }
        int il = iloc + rr;
        int sw = lane ^ ((il & 7) << 2);
        NS[(size_t)il * 64 + sw] = (unsigned)f2bf(s0) | ((unsigned)f2bf(s1) << 16);
      }
    } else {                                     // tail: per-row, clamp to 29999
#pragma unroll
      for (int rr = 0; rr < 4; ++rr) {
        int r = r0 + rr;
        int rc = (r > DEG_COUNT - 1) ? (DEG_COUNT - 1) : r;
        nsum_row1<D>(atomsU, abase, NS, iloc + rr, rc, lane);
      }
    }
  }
}

// ---------------------------------------------------------------------------
// K3: fused nsum + streaming MFMA GEMM — activated half (128 cols).
// Round-14 structure (64KB single-stage B; split-K falsified in r15: gather
// is memory-path-bound, occupancy doubling changed nothing).
// ---------------------------------------------------------------------------
__global__ __launch_bounds__(512, 4) void k_gemm(
    const unsigned short* __restrict__ atomsBf,
    AdjPtrs adj,
    const unsigned short* __restrict__ BcatT,    // [11][128][256] n-major
    const float* __restrict__ biascat,           // [11][128]
    const float* __restrict__ gamma,
    const float* __restrict__ beta,
    float* __restrict__ out0)                    // xn FINAL (fp32)
{
  const int d = blockIdx.y;
  const int rowTile = blockIdx.x;
  const int tid = threadIdx.x;
  const int lane = tid & 63;
  const int wave = tid >> 6;          // 0..7
  const int m16 = lane & 15;
  const int g = lane >> 4;            // k-group 0..3

  __shared__ unsigned short Bs[128 * 256];   // 64 KiB; phase0 NS uses first 32KB
  unsigned* NS = (unsigned*)Bs;              // [128 rows][64 words], swizzled

  const unsigned short* Bd = BcatT + d * 32768;
  const unsigned* atomsU = (const unsigned*)atomsBf;

  // ---- self A-frags (ks 4-7) from global first (overlap with phase 0) ----
  const int rowBase = rowTile * 128 + wave * 16;
  bf16x8 af[8];
  {
    int rbL = rowBase + m16; if (rbL > DEG_COUNT - 1) rbL = DEG_COUNT - 1;
    size_t gr = (size_t)d * DEG_COUNT + rbL;
#pragma unroll
    for (int ks = 4; ks < 8; ++ks)
      af[ks] = *(const bf16x8*)(atomsBf + gr * 128 + (ks - 4) * 32 + g * 8);
  }

  // ---- phase 0: fused nsum into LDS; af ks0-3 from LDS ----
  if (d > 0) {
    const int* abase = adj.p[d - 1];
    switch (d) {
      case 1:  nsum_phase0<1>(atomsU, abase, NS, rowTile, wave, lane); break;
      case 2:  nsum_phase0<2>(atomsU, abase, NS, rowTile, wave, lane); break;
      case 3:  nsum_phase0<3>(atomsU, abase, NS, rowTile, wave, lane); break;
      case 4:  nsum_phase0<4>(atomsU, abase, NS, rowTile, wave, lane); break;
      case 5:  nsum_phase0<5>(atomsU, abase, NS, rowTile, wave, lane); break;
      case 6:  nsum_phase0<6>(atomsU, abase, NS, rowTile, wave, lane); break;
      case 7:  nsum_phase0<7>(atomsU, abase, NS, rowTile, wave, lane); break;
      case 8:  nsum_phase0<8>(atomsU, abase, NS, rowTile, wave, lane); break;
      case 9:  nsum_phase0<9>(atomsU, abase, NS, rowTile, wave, lane); break;
      default: nsum_phase0<10>(atomsU, abase, NS, rowTile, wave, lane); break;
    }
    __syncthreads();
    const char* nsb = (const char*)NS;
    const int rowb = (wave * 16 + m16) * 256;         // byte base, local row
    const int sw = (m16 & 7) << 4;
#pragma unroll
    for (int ks = 0; ks < 4; ++ks)
      af[ks] = *(const bf16x8*)(nsb + ((rowb + ks * 64 + g * 16) ^ sw));
    __syncthreads();   // protect NS before B-panel overwrite
  } else {
    bf16x8 z = {0, 0, 0, 0, 0, 0, 0, 0};
#pragma unroll
    for (int ks = 0; ks < 4; ++ks) af[ks] = z;
  }

  // ---- stage B: 512 threads x 8 x 16B = 64KB, swizzled dest ----
#pragma unroll
  for (int it = 0; it < 8; ++it) {
    int flat = it * 512 + tid;        // chunk of 16B; 32 chunks per row
    int row = flat >> 5;              // 0..127
    int c = flat & 31;
    uint4 v = *(const uint4*)(Bd + row * 256 + c * 8);
    int kb = (c * 16) ^ ((row & 7) << 4);
    *(uint4*)((char*)Bs + row * 512 + kb) = v;
  }

  __syncthreads();

  const int ldsMask = (m16 & 7) << 4;

  f32x4 acc[8];
#pragma unroll
  for (int ct = 0; ct < 8; ++ct) acc[ct] = (f32x4){0.f, 0.f, 0.f, 0.f};

#pragma unroll
  for (int ct = 0; ct < 8; ++ct) {
    const char* bbase = (const char*)Bs + (ct * 16 + m16) * 512;
    bf16x8 bf[8];
#pragma unroll
    for (int ks = 0; ks < 8; ++ks)
      bf[ks] = *(const bf16x8*)(bbase + ((ks * 64 + g * 16) ^ ldsMask));
#pragma unroll
    for (int ks = 0; ks < 8; ++ks)
      acc[ct] = __builtin_amdgcn_mfma_f32_16x16x32_bf16(af[ks], bf[ks], acc[ct], 0, 0, 0);
  }

  // ---- epilogue: bias, LN over 128 cols, coalesced stores ----
  float bias_[8], gam[8], bet[8];
#pragma unroll
  for (int ct = 0; ct < 8; ++ct) {
    bias_[ct] = biascat[d * 128 + ct * 16 + m16];
    gam[ct] = gamma[ct * 16 + m16];
    bet[ct] = beta[ct * 16 + m16];
  }

#pragma unroll
  for (int ct = 0; ct < 8; ++ct)
#pragma unroll
    for (int r = 0; r < 4; ++r) acc[ct][r] += bias_[ct];

  float s[4], qq[4];
#pragma unroll
  for (int r = 0; r < 4; ++r) {
    s[r] = 0.f; qq[r] = 0.f;
#pragma unroll
    for (int ct = 0; ct < 8; ++ct) {
      float v = acc[ct][r];
      s[r] += v; qq[r] += v * v;
    }
  }
#pragma unroll
  for (int off = 8; off >= 1; off >>= 1) {
#pragma unroll
    for (int r = 0; r < 4; ++r) {
      s[r]  += __shfl_xor(s[r],  off, 64);
      qq[r] += __shfl_xor(qq[r], off, 64);
    }
  }

#pragma unroll
  for (int r = 0; r < 4; ++r) {
    int rb = rowBase + g * 4 + r;
    float mean = s[r] * (1.0f / 128.0f);
    float var  = qq[r] * (1.0f / 128.0f) - mean * mean;
    float inv  = 1.0f / (sqrtf(var + 1e-5f) + 1e-5f);   // ref: sqrt(var+eps)+eps
    if (rb < DEG_COUNT) {
      size_t grow = (size_t)d * DEG_COUNT + rb;
#pragma unroll
      for (int ct = 0; ct < 8; ++ct)
        out0[grow * 128 + ct * 16 + m16] = gam[ct] * ((acc[ct][r] - mean) * inv) + bet[ct];
    }
  }
}

// ---------------------------------------------------------------------------
// K_mreduce: ONE perm pass doing BOTH segment-max(xn) AND per-(molecule,
// degree) atom sums + counts. Per-wave LDS tables with PLAIN adds.
// NSLICES=4 (round-14 config; 8 regressed).
// ---------------------------------------------------------------------------
__global__ __launch_bounds__(512) void k_mreduce(
    const f32x2* __restrict__ xnV,          // out0 as f32x2
    const unsigned* __restrict__ atomsU,
    const int* __restrict__ perm,
    const int* __restrict__ tot,            // [128]
    float* __restrict__ Spart,      // [NSLICES][128][11][128]
    int* __restrict__ cntPart,      // [NSLICES][128][11]
    float2* __restrict__ pmax4)     // [NSLICES][128][64] float2
{
  const int m = blockIdx.x >> 2;
  const int s = blockIdx.x & 3;
  const int wave = threadIdx.x >> 6, lane = threadIdx.x & 63;

  __shared__ float S[8][11][128];   // physical col p: p<64 -> col 2p, else 2(p-64)+1
  __shared__ int C[8][11];
  __shared__ float2 maxT[8][64];
  __shared__ int totS[BATCH];
  __shared__ int rangeS[2];
  for (int e = lane; e < 11 * 128; e += 64) S[wave][e >> 7][e & 127] = 0.f;
  if (lane < 11) C[wave][lane] = 0;
  if (threadIdx.x < BATCH) totS[threadIdx.x] = tot[threadIdx.x];
  __syncthreads();
  if (threadIdx.x == 0) {
    int a = 0;
    for (int i = 0; i < m; ++i) a += totS[i];
    rangeS[0] = a; rangeS[1] = totS[m];
  }
  __syncthreads();
  const int b0 = rangeS[0], cnt = rangeS[1];
  const int lo = b0 + (cnt * s) / NSLICES;
  const int hi = b0 + (cnt * (s + 1)) / NSLICES;

  const float NEG_INF = __int_as_float((int)NEG_INF_BITS);
  float mx0 = NEG_INF, mx1 = NEG_INF;

  for (int i = lo + wave * 2; i < hi; i += 16) {
    int r0 = perm[i];
    bool has1 = (i + 1 < hi);
    int r1 = has1 ? perm[i + 1] : r0;
    f32x2 x0 = __builtin_nontemporal_load(xnV + (size_t)r0 * 64 + lane);
    unsigned a0 = __builtin_nontemporal_load(atomsU + (size_t)r0 * 64 + lane);
    f32x2 x1 = __builtin_nontemporal_load(xnV + (size_t)r1 * 64 + lane);
    unsigned a1 = __builtin_nontemporal_load(atomsU + (size_t)r1 * 64 + lane);
    int d0 = r0 / DEG_COUNT;                    // wave-uniform
    mx0 = fmaxf(mx0, x0[0]);
    mx1 = fmaxf(mx1, x0[1]);
    S[wave][d0][lane]      += bf2f((unsigned short)(a0 & 0xffff));   // plain LDS add
    S[wave][d0][64 + lane] += bf2f((unsigned short)(a0 >> 16));
    if (lane == 0) C[wave][d0]++;
    if (has1) {
      int d1 = r1 / DEG_COUNT;
      mx0 = fmaxf(mx0, x1[0]);
      mx1 = fmaxf(mx1, x1[1]);
      S[wave][d1][lane]      += bf2f((unsigned short)(a1 & 0xffff));
      S[wave][d1][64 + lane] += bf2f((unsigned short)(a1 >> 16));
      if (lane == 0) C[wave][d1]++;
    }
  }
  maxT[wave][lane] = make_float2(mx0, mx1);
  __syncthreads();

  if (threadIdx.x < 64) {
    int l = threadIdx.x;
    float2 mm = maxT[0][l];
#pragma unroll
    for (int w = 1; w < 8; ++w) {
      float2 b = maxT[w][l]; mm.x = fmaxf(mm.x, b.x); mm.y = fmaxf(mm.y, b.y);
    }
    pmax4[((size_t)s * 128 + m) * 64 + l] = mm;
  }
  for (int e = threadIdx.x; e < 11 * 128; e += 512) {
    int d = e >> 7, p = e & 127;
    float t = 0.f;
#pragma unroll
    for (int w = 0; w < 8; ++w) t += S[w][d][p];
    int col = (p < 64) ? (2 * p) : (2 * (p - 64) + 1);   // de-permute
    Spart[(((size_t)s * 128 + m) * 11 + d) * 128 + col] = t;
  }
  if (threadIdx.x < 11) {
    int t = 0;
#pragma unroll
    for (int w = 0; w < 8; ++w) t += C[w][threadIdx.x];
    cntPart[((size_t)s * 128 + m) * 11 + threadIdx.x] = t;
  }
}

// ---------------------------------------------------------------------------
// K_ynfinal: yn = LN( sum_d S[m,d] @ Wg_d + cnt[m,d]*bg_d ) -> out1, and
// merge NSLICES max slices -> out2. 128 blocks x 128 threads.
// ---------------------------------------------------------------------------
__global__ __launch_bounds__(128) void k_ynfinal(
    const float* __restrict__ Spart,
    const int* __restrict__ cntPart,
    const float* __restrict__ W,
    const float* __restrict__ b,
    const float* __restrict__ gamma,
    const float* __restrict__ beta,
    const float* __restrict__ pmax4,        // [NSLICES][128][128]
    float* __restrict__ out1,
    float* __restrict__ out2)
{
  int m = blockIdx.x;
  int j = threadIdx.x;

  float g = __int_as_float((int)NEG_INF_BITS);
#pragma unroll
  for (int sl = 0; sl < NSLICES; ++sl)
    g = fmaxf(g, pmax4[((size_t)sl * 128 + m) * 128 + j]);
  out2[m * 128 + j] = g;

  __shared__ float Sm[11][128];
  __shared__ float cw[11];
  for (int e = j; e < 11 * 128; e += 128) {
    int d = e >> 7, c = e & 127;
    float t = 0.f;
#pragma unroll
    for (int sl = 0; sl < NSLICES; ++sl)
      t += Spart[(((size_t)sl * 128 + m) * 11 + d) * 128 + c];
    Sm[d][c] = t;
  }
  if (j < 11) {
    int t = 0;
#pragma unroll
    for (int sl = 0; sl < NSLICES; ++sl)
      t += cntPart[((size_t)sl * 128 + m) * 11 + j];
    cw[j] = (float)t;
  }
  __syncthreads();

  float acc = 0.f;
  for (int d = 0; d < 11; ++d) {
    int wi = (d >= 1) ? (20 + d) : 31;
    const float* Wd = W + wi * 16384;
    float a0 = 0.f, a1 = 0.f, a2 = 0.f, a3 = 0.f;
    for (int k = 0; k < 128; k += 4) {
      a0 += Sm[d][k]     * Wd[k * 128 + j];
      a1 += Sm[d][k + 1] * Wd[(k + 1) * 128 + j];
      a2 += Sm[d][k + 2] * Wd[(k + 2) * 128 + j];
      a3 += Sm[d][k + 3] * Wd[(k + 3) * 128 + j];
    }
    acc += (a0 + a1) + (a2 + a3);
    acc += cw[d] * b[wi * 128 + j];
  }

  float ws_ = acc, wq = acc * acc;
#pragma unroll
  for (int off = 32; off >= 1; off >>= 1) {
    ws_ += __shfl_xor(ws_, off, 64);
    wq  += __shfl_xor(wq, off, 64);
  }
  __shared__ float red[4];
  int wave = j >> 6, lane = j & 63;
  if (lane == 0) { red[wave * 2] = ws_; red[wave * 2 + 1] = wq; }
  __syncthreads();
  float Ssum = red[0] + red[2], Q = red[1] + red[3];
  float mean = Ssum * (1.f / 128.f);
  float var = Q * (1.f / 128.f) - mean * mean;
  float inv = 1.f / (sqrtf(var + 1e-5f) + 1e-5f);
  out1[m * 128 + j] = gamma[j] * ((acc - mean) * inv) + beta[j];
}

// ---------------------------------------------------------------------------
extern "C" void kernel_launch(void* const* d_in, const int* in_sizes, int n_in,
                              void* d_out, int out_size, void* d_ws, size_t ws_size,
                              hipStream_t stream) {
  const float* atoms = (const float*)d_in[0];
  // d_in[1] = deg_slice (unused; buckets are static)
  const int* membership = (const int*)d_in[2];
  AdjPtrs adj;
  for (int i = 0; i < 10; ++i) adj.p[i] = (const int*)d_in[3 + i];
  const float* W     = (const float*)d_in[13];
  const float* b     = (const float*)d_in[14];
  const float* gamma = (const float*)d_in[15];
  const float* beta  = (const float*)d_in[16];

  char* ws = (char*)d_ws;
  size_t off = 0;
  unsigned short* atomsBf = (unsigned short*)(ws + off); off += (size_t)N_ATOMS * 128 * 2;
  unsigned short* BcatT   = (unsigned short*)(ws + off); off += (size_t)11 * 128 * 256 * 2;
  float* biascat          = (float*)(ws + off);          off += (size_t)11 * 128 * 4;
  int* perm               = (int*)(ws + off);            off += (size_t)N_ATOMS * 4;
  int* tot                = (int*)(ws + off);            off += 512;
  int* blockHistT         = (int*)(ws + off);            off += (size_t)BATCH * SORT_BLOCKS * 4;
  int* relOffT            = (int*)(ws + off);            off += (size_t)BATCH * SORT_BLOCKS * 4;
  float* Spart            = (float*)(ws + off);          off += (size_t)NSLICES * 128 * 11 * 128 * 4;
  int* cntPart            = (int*)(ws + off);            off += (size_t)NSLICES * 128 * 11 * 4;
  float* pmax4            = (float*)(ws + off);          off += (size_t)NSLICES * 128 * 128 * 4;

  float* out0 = (float*)d_out;
  float* out1 = out0 + (size_t)N_ATOMS * 128;
  float* out2 = out1 + 16384;

  // 1) build B/bias + cast + histogram (block-range dispatch, one launch)
  hipLaunchKernelGGL(k_prep, dim3(NB_BUILD + NB_CAST + SORT_BLOCKS), dim3(256), 0, stream,
                     W, b, (const f32x4*)atoms, membership,
                     BcatT, biascat, (ushort4*)atomsBf, blockHistT);
  // 2) parallel scan -> relOffT + tot
  hipLaunchKernelGGL(k_scan, dim3(128), dim3(256), 0, stream, blockHistT, relOffT, tot);
  // 3) scatter -> perm
  hipLaunchKernelGGL(k_scatter, dim3(SORT_BLOCKS), dim3(256), 0, stream,
                     membership, relOffT, tot, perm);
  // 4) fused nsum (4-row MLP) + activated GEMM + LN (round-14 structure)
  hipLaunchKernelGGL(k_gemm, dim3(236, 11), dim3(512), 0, stream,
                     atomsBf, adj, BcatT, biascat, gamma, beta, out0);
  // 5) fused segment-max(xn) + per-(mol,deg) atom sums (single perm pass)
  hipLaunchKernelGGL(k_mreduce, dim3(128 * NSLICES), dim3(512), 0, stream,
                     (const f32x2*)out0, (const unsigned*)atomsBf, perm, tot,
                     Spart, cntPart, (float2*)pmax4);
  // 6) yn (algebraic gathered path) + max merge
  hipLaunchKernelGGL(k_ynfinal, dim3(128), dim3(128), 0, stream,
                     Spart, cntPart, W, b, gamma, beta, pmax4, out1, out2);
}

// Round 17
// 474.951 us; speedup vs baseline: 1.0713x; 1.0369x over previous
//
#include <hip/hip_runtime.h>
#include <stdint.h>

#define MAX_DEG   10
#define DEG_COUNT 30000
#define N_ATOMS   330000      // 11 * 30000
#define NF        128
#define BATCH     128
#define SORT_BLOCKS 256
#define SORT_CHUNK  1290      // ceil(330000/256)
#define NB_BUILD  1408        // 11*128*256/256
#define NB_CAST   20625       // N_ATOMS*128/4/512 (2 float4 per thread)
#define NSLICES   4           // mreduce slices per molecule (8 regressed, r15)

typedef __attribute__((ext_vector_type(8))) short bf16x8;   // 8 bf16 (4 VGPRs)
typedef __attribute__((ext_vector_type(4))) float f32x4;
typedef __attribute__((ext_vector_type(2))) float f32x2;

__device__ __forceinline__ float bf2f(unsigned short h) {
  union { unsigned u; float f; } v; v.u = ((unsigned)h) << 16; return v.f;
}
__device__ __forceinline__ unsigned short f2bf(float f) {
  union { float f; unsigned u; } v; v.f = f;
  unsigned u = v.u;
  unsigned r = (u + 0x7fffu + ((u >> 16) & 1u)) >> 16;   // RNE
  return (unsigned short)r;
}

struct AdjPtrs { const int* p[10]; };

#define NEG_INF_BITS 0xFF800000

// ---------------------------------------------------------------------------
// K_prep: block-range dispatch — three independent jobs, one launch, each at
// its natural parallelism. Cast now does 2 float4 per thread (ILP).
// ---------------------------------------------------------------------------
__global__ __launch_bounds__(256) void k_prep(
    const float* __restrict__ W,
    const float* __restrict__ b,
    const f32x4* __restrict__ atoms4,
    const int* __restrict__ membership,
    unsigned short* __restrict__ BcatT,     // [11][128][256]
    float* __restrict__ biascat,            // [11][128]
    ushort4* __restrict__ dst4,             // bf16 atoms copy
    int* __restrict__ blockHistT)           // [128 m][256 b]
{
  const int bx = blockIdx.x;
  const int tid = threadIdx.x;
  __shared__ int bins[BATCH];

  if (bx < NB_BUILD) {
    int idx = bx * 256 + tid;
    if (idx < 11 * 128) {           // bias: [d][n]
      int d = idx >> 7, n = idx & 127;
      float f = (d >= 1) ? (b[(2 * (d - 1)) * 128 + n] + b[(2 * d - 1) * 128 + n])
                         : b[20 * 128 + n];
      biascat[idx] = f;
    }
    if (idx < 11 * 128 * 256) {
      int d = idx >> 15;
      int rem = idx & 32767;
      int n = rem >> 8;
      int k = rem & 255;
      float v;
      if (k < 128) {
        v = (d >= 1) ? W[(2 * (d - 1)) * 16384 + k * 128 + n] : 0.f;
      } else {
        int ks = k - 128;
        int wi = (d >= 1) ? (2 * d - 1) : 20;
        v = W[wi * 16384 + ks * 128 + n];
      }
      BcatT[idx] = f2bf(v);   // idx == d*32768 + n*256 + k
    }
  } else if (bx < NB_BUILD + NB_CAST) {
    size_t base = (size_t)(bx - NB_BUILD) * 512 + tid;   // 2 float4 per thread
    f32x4 v0 = __builtin_nontemporal_load(atoms4 + base);
    f32x4 v1 = __builtin_nontemporal_load(atoms4 + base + 256);
    ushort4 o0, o1;
    o0.x = f2bf(v0[0]); o0.y = f2bf(v0[1]); o0.z = f2bf(v0[2]); o0.w = f2bf(v0[3]);
    o1.x = f2bf(v1[0]); o1.y = f2bf(v1[1]); o1.z = f2bf(v1[2]); o1.w = f2bf(v1[3]);
    dst4[base] = o0;
    dst4[base + 256] = o1;
  } else {
    int bh = bx - NB_BUILD - NB_CAST;     // 0..SORT_BLOCKS-1
    if (tid < BATCH) bins[tid] = 0;
    __syncthreads();
    int lo = bh * SORT_CHUNK, hi = min(lo + SORT_CHUNK, N_ATOMS);
    for (int i = lo + tid; i < hi; i += 256)
      atomicAdd(&bins[membership[i]], 1);
    __syncthreads();
    if (tid < BATCH) blockHistT[tid * 256 + bh] = bins[tid];
  }
}

// ---------------------------------------------------------------------------
// K_scan: parallel scan. 128 blocks (one per molecule) x 256 threads.
// ---------------------------------------------------------------------------
__global__ __launch_bounds__(256) void k_scan(
    const int* __restrict__ blockHistT,     // [128 m][256 b]
    int* __restrict__ relOffT,              // [128 m][256 b] exclusive
    int* __restrict__ tot)                  // [128]
{
  const int m = blockIdx.x;
  const int tid = threadIdx.x;              // = b
  __shared__ int ws[4];
  int v = blockHistT[m * 256 + tid];
  int x = v;
#pragma unroll
  for (int o = 1; o < 64; o <<= 1) {
    int t = __shfl_up(x, o, 64);
    if ((tid & 63) >= o) x += t;
  }
  if ((tid & 63) == 63) ws[tid >> 6] = x;
  __syncthreads();
  int wb = 0;
  for (int w = 0; w < (tid >> 6); ++w) wb += ws[w];
  int incl = wb + x;
  relOffT[m * 256 + tid] = incl - v;
  if (tid == 255) tot[m] = incl;
}

// K_scatter: seed LDS bins with base[m] + this chunk's offsets, then
// block-local native int LDS atomics + plain 4B writes.
__global__ __launch_bounds__(256) void k_scatter(
    const int* __restrict__ membership,
    const int* __restrict__ relOffT,
    const int* __restrict__ tot,
    int* __restrict__ perm)
{
  __shared__ int totS[BATCH], baseS[BATCH], bins[BATCH];
  const int tid = threadIdx.x;
  if (tid < BATCH) totS[tid] = tot[tid];
  __syncthreads();
  if (tid == 0) {
    int a = 0;
    for (int i = 0; i < BATCH; ++i) { baseS[i] = a; a += totS[i]; }
  }
  __syncthreads();
  if (tid < BATCH) bins[tid] = baseS[tid] + relOffT[tid * 256 + blockIdx.x];
  __syncthreads();
  int lo = blockIdx.x * SORT_CHUNK, hi = min(lo + SORT_CHUNK, N_ATOMS);
  for (int i = lo + tid; i < hi; i += 256) {
    int m = membership[i];
    int pos = atomicAdd(&bins[m], 1);   // native int LDS atomic
    perm[pos] = i;
  }
}

// ---------------------------------------------------------------------------
// Phase-0 helper (fused nsum): one wave computes 16 nsum rows of its block
// into LDS, 4 rows/iter (4D <= 40 gathers in flight; r16 win). Accumulation
// j-ascending per row => bit-identical. Tail falls back per-row clamped.
// ---------------------------------------------------------------------------
template<int D>
__device__ __forceinline__ void nsum_row1(const unsigned* __restrict__ atomsU,
                                          const int* __restrict__ abase,
                                          unsigned* __restrict__ NS,
                                          int iloc, int rclamp, int lane) {
  const int* a = abase + (size_t)rclamp * D;
  int myIdx = (lane < D) ? a[lane] : 0;
  unsigned xs[D];
#pragma unroll
  for (int j = 0; j < D; ++j) {
    int nbr = __shfl(myIdx, j, 64);
    xs[j] = atomsU[(size_t)nbr * 64 + lane];
  }
  float s0 = 0.f, s1 = 0.f;
#pragma unroll
  for (int j = 0; j < D; ++j) {
    s0 += bf2f((unsigned short)(xs[j] & 0xffff));
    s1 += bf2f((unsigned short)(xs[j] >> 16));
  }
  int sw = lane ^ ((iloc & 7) << 2);
  NS[(size_t)iloc * 64 + sw] = (unsigned)f2bf(s0) | ((unsigned)f2bf(s1) << 16);
}

template<int D>
__device__ __forceinline__ void nsum_phase0(const unsigned* __restrict__ atomsU,
                                            const int* __restrict__ abase,
                                            unsigned* __restrict__ NS,
                                            int rowTile, int wave, int lane) {
  for (int it = 0; it < 4; ++it) {
    int iloc = wave * 16 + it * 4;               // local row 0..127, 4 rows
    int r0 = rowTile * 128 + iloc;
    if (r0 + 3 < DEG_COUNT) {                    // fast path: rows r0..r0+3
      const int* a = abase + (size_t)r0 * D;
      int myIdx = (lane < 4 * D) ? a[lane] : 0;
      unsigned xs[4 * D];
#pragma unroll
      for (int j = 0; j < 4 * D; ++j) {
        int nbr = __shfl(myIdx, j, 64);
        xs[j] = atomsU[(size_t)nbr * 64 + lane];
      }
#pragma unroll
      for (int rr = 0; rr < 4; ++rr) {
        float s0 = 0.f, s1 = 0.f;
#pragma unroll
        for (int j = rr * D; j < (rr + 1) * D; ++j) {
          s0 += bf2f((unsigned short)(xs[j] & 0xffff));
          s1 += bf2f((unsigned short)(xs[j] >> 16));
        }
        int il = iloc + rr;
        int sw = lane ^ ((il & 7) << 2);
        NS[(size_t)il * 64 + sw] = (unsigned)f2bf(s0) | ((unsigned)f2bf(s1) << 16);
      }
    } else {                                     // tail: per-row, clamp to 29999
#pragma unroll
      for (int rr = 0; rr < 4; ++rr) {
        int r = r0 + rr;
        int rc = (r > DEG_COUNT - 1) ? (DEG_COUNT - 1) : r;
        nsum_row1<D>(atomsU, abase, NS, iloc + rr, rc, lane);
      }
    }
  }
}

// ---------------------------------------------------------------------------
// K3: fused nsum + streaming MFMA GEMM — activated half (128 cols).
// NEW (clean test of r13's confounded idea): 1D grid, d = bid % 11 —
// round-robin interleaves heavy d=10 blocks across the dispatch instead of
// clustering them in the tail. Body byte-identical to r16.
// ---------------------------------------------------------------------------
__global__ __launch_bounds__(512, 4) void k_gemm(
    const unsigned short* __restrict__ atomsBf,
    AdjPtrs adj,
    const unsigned short* __restrict__ BcatT,    // [11][128][256] n-major
    const float* __restrict__ biascat,           // [11][128]
    const float* __restrict__ gamma,
    const float* __restrict__ beta,
    float* __restrict__ out0)                    // xn FINAL (fp32)
{
  const int bid = blockIdx.x;
  const int d = bid % 11;
  const int rowTile = bid / 11;
  const int tid = threadIdx.x;
  const int lane = tid & 63;
  const int wave = tid >> 6;          // 0..7
  const int m16 = lane & 15;
  const int g = lane >> 4;            // k-group 0..3

  __shared__ unsigned short Bs[128 * 256];   // 64 KiB; phase0 NS uses first 32KB
  unsigned* NS = (unsigned*)Bs;              // [128 rows][64 words], swizzled

  const unsigned short* Bd = BcatT + d * 32768;
  const unsigned* atomsU = (const unsigned*)atomsBf;

  // ---- self A-frags (ks 4-7) from global first (overlap with phase 0) ----
  const int rowBase = rowTile * 128 + wave * 16;
  bf16x8 af[8];
  {
    int rbL = rowBase + m16; if (rbL > DEG_COUNT - 1) rbL = DEG_COUNT - 1;
    size_t gr = (size_t)d * DEG_COUNT + rbL;
#pragma unroll
    for (int ks = 4; ks < 8; ++ks)
      af[ks] = *(const bf16x8*)(atomsBf + gr * 128 + (ks - 4) * 32 + g * 8);
  }

  // ---- phase 0: fused nsum into LDS; af ks0-3 from LDS ----
  if (d > 0) {
    const int* abase = adj.p[d - 1];
    switch (d) {
      case 1:  nsum_phase0<1>(atomsU, abase, NS, rowTile, wave, lane); break;
      case 2:  nsum_phase0<2>(atomsU, abase, NS, rowTile, wave, lane); break;
      case 3:  nsum_phase0<3>(atomsU, abase, NS, rowTile, wave, lane); break;
      case 4:  nsum_phase0<4>(atomsU, abase, NS, rowTile, wave, lane); break;
      case 5:  nsum_phase0<5>(atomsU, abase, NS, rowTile, wave, lane); break;
      case 6:  nsum_phase0<6>(atomsU, abase, NS, rowTile, wave, lane); break;
      case 7:  nsum_phase0<7>(atomsU, abase, NS, rowTile, wave, lane); break;
      case 8:  nsum_phase0<8>(atomsU, abase, NS, rowTile, wave, lane); break;
      case 9:  nsum_phase0<9>(atomsU, abase, NS, rowTile, wave, lane); break;
      default: nsum_phase0<10>(atomsU, abase, NS, rowTile, wave, lane); break;
    }
    __syncthreads();
    const char* nsb = (const char*)NS;
    const int rowb = (wave * 16 + m16) * 256;         // byte base, local row
    const int sw = (m16 & 7) << 4;
#pragma unroll
    for (int ks = 0; ks < 4; ++ks)
      af[ks] = *(const bf16x8*)(nsb + ((rowb + ks * 64 + g * 16) ^ sw));
    __syncthreads();   // protect NS before B-panel overwrite
  } else {
    bf16x8 z = {0, 0, 0, 0, 0, 0, 0, 0};
#pragma unroll
    for (int ks = 0; ks < 4; ++ks) af[ks] = z;
  }

  // ---- stage B: 512 threads x 8 x 16B = 64KB, swizzled dest ----
#pragma unroll
  for (int it = 0; it < 8; ++it) {
    int flat = it * 512 + tid;        // chunk of 16B; 32 chunks per row
    int row = flat >> 5;              // 0..127
    int c = flat & 31;
    uint4 v = *(const uint4*)(Bd + row * 256 + c * 8);
    int kb = (c * 16) ^ ((row & 7) << 4);
    *(uint4*)((char*)Bs + row * 512 + kb) = v;
  }

  __syncthreads();

  const int ldsMask = (m16 & 7) << 4;

  f32x4 acc[8];
#pragma unroll
  for (int ct = 0; ct < 8; ++ct) acc[ct] = (f32x4){0.f, 0.f, 0.f, 0.f};

#pragma unroll
  for (int ct = 0; ct < 8; ++ct) {
    const char* bbase = (const char*)Bs + (ct * 16 + m16) * 512;
    bf16x8 bf[8];
#pragma unroll
    for (int ks = 0; ks < 8; ++ks)
      bf[ks] = *(const bf16x8*)(bbase + ((ks * 64 + g * 16) ^ ldsMask));
#pragma unroll
    for (int ks = 0; ks < 8; ++ks)
      acc[ct] = __builtin_amdgcn_mfma_f32_16x16x32_bf16(af[ks], bf[ks], acc[ct], 0, 0, 0);
  }

  // ---- epilogue: bias, LN over 128 cols, coalesced stores ----
  float bias_[8], gam[8], bet[8];
#pragma unroll
  for (int ct = 0; ct < 8; ++ct) {
    bias_[ct] = biascat[d * 128 + ct * 16 + m16];
    gam[ct] = gamma[ct * 16 + m16];
    bet[ct] = beta[ct * 16 + m16];
  }

#pragma unroll
  for (int ct = 0; ct < 8; ++ct)
#pragma unroll
    for (int r = 0; r < 4; ++r) acc[ct][r] += bias_[ct];

  float s[4], qq[4];
#pragma unroll
  for (int r = 0; r < 4; ++r) {
    s[r] = 0.f; qq[r] = 0.f;
#pragma unroll
    for (int ct = 0; ct < 8; ++ct) {
      float v = acc[ct][r];
      s[r] += v; qq[r] += v * v;
    }
  }
#pragma unroll
  for (int off = 8; off >= 1; off >>= 1) {
#pragma unroll
    for (int r = 0; r < 4; ++r) {
      s[r]  += __shfl_xor(s[r],  off, 64);
      qq[r] += __shfl_xor(qq[r], off, 64);
    }
  }

#pragma unroll
  for (int r = 0; r < 4; ++r) {
    int rb = rowBase + g * 4 + r;
    float mean = s[r] * (1.0f / 128.0f);
    float var  = qq[r] * (1.0f / 128.0f) - mean * mean;
    float inv  = 1.0f / (sqrtf(var + 1e-5f) + 1e-5f);   // ref: sqrt(var+eps)+eps
    if (rb < DEG_COUNT) {
      size_t grow = (size_t)d * DEG_COUNT + rb;
#pragma unroll
      for (int ct = 0; ct < 8; ++ct)
        out0[grow * 128 + ct * 16 + m16] = gam[ct] * ((acc[ct][r] - mean) * inv) + bet[ct];
    }
  }
}

// ---------------------------------------------------------------------------
// K_mreduce: ONE perm pass doing BOTH segment-max(xn) AND per-(molecule,
// degree) atom sums + counts. Per-wave LDS tables with PLAIN adds.
// NOW 4 rows/iter (12 loads in flight/wave — same MLP lever as gemm r16).
// S-sum order changes (fp32, tolerance has 3+ orders of slack); max is
// order-free; xn untouched.
// ---------------------------------------------------------------------------
__global__ __launch_bounds__(512) void k_mreduce(
    const f32x2* __restrict__ xnV,          // out0 as f32x2
    const unsigned* __restrict__ atomsU,
    const int* __restrict__ perm,
    const int* __restrict__ tot,            // [128]
    float* __restrict__ Spart,      // [NSLICES][128][11][128]
    int* __restrict__ cntPart,      // [NSLICES][128][11]
    float2* __restrict__ pmax4)     // [NSLICES][128][64] float2
{
  const int m = blockIdx.x >> 2;
  const int s = blockIdx.x & 3;
  const int wave = threadIdx.x >> 6, lane = threadIdx.x & 63;

  __shared__ float S[8][11][128];   // physical col p: p<64 -> col 2p, else 2(p-64)+1
  __shared__ int C[8][11];
  __shared__ float2 maxT[8][64];
  __shared__ int totS[BATCH];
  __shared__ int rangeS[2];
  for (int e = lane; e < 11 * 128; e += 64) S[wave][e >> 7][e & 127] = 0.f;
  if (lane < 11) C[wave][lane] = 0;
  if (threadIdx.x < BATCH) totS[threadIdx.x] = tot[threadIdx.x];
  __syncthreads();
  if (threadIdx.x == 0) {
    int a = 0;
    for (int i = 0; i < m; ++i) a += totS[i];
    rangeS[0] = a; rangeS[1] = totS[m];
  }
  __syncthreads();
  const int b0 = rangeS[0], cnt = rangeS[1];
  const int lo = b0 + (cnt * s) / NSLICES;
  const int hi = b0 + (cnt * (s + 1)) / NSLICES;

  const float NEG_INF = __int_as_float((int)NEG_INF_BITS);
  float mx0 = NEG_INF, mx1 = NEG_INF;

  for (int i = lo + wave * 4; i < hi; i += 32) {
    int rr[4];
    bool hv[4];
#pragma unroll
    for (int k = 0; k < 4; ++k) {
      hv[k] = (i + k < hi);
      rr[k] = hv[k] ? perm[i + k] : perm[i];
    }
    f32x2 xx[4];
    unsigned aa[4];
#pragma unroll
    for (int k = 0; k < 4; ++k) {
      xx[k] = __builtin_nontemporal_load(xnV + (size_t)rr[k] * 64 + lane);
      aa[k] = __builtin_nontemporal_load(atomsU + (size_t)rr[k] * 64 + lane);
    }
#pragma unroll
    for (int k = 0; k < 4; ++k) {
      if (!hv[k]) continue;
      int dk = rr[k] / DEG_COUNT;               // wave-uniform
      mx0 = fmaxf(mx0, xx[k][0]);
      mx1 = fmaxf(mx1, xx[k][1]);
      S[wave][dk][lane]      += bf2f((unsigned short)(aa[k] & 0xffff));  // plain LDS add
      S[wave][dk][64 + lane] += bf2f((unsigned short)(aa[k] >> 16));
      if (lane == 0) C[wave][dk]++;
    }
  }
  maxT[wave][lane] = make_float2(mx0, mx1);
  __syncthreads();

  if (threadIdx.x < 64) {
    int l = threadIdx.x;
    float2 mm = maxT[0][l];
#pragma unroll
    for (int w = 1; w < 8; ++w) {
      float2 b = maxT[w][l]; mm.x = fmaxf(mm.x, b.x); mm.y = fmaxf(mm.y, b.y);
    }
    pmax4[((size_t)s * 128 + m) * 64 + l] = mm;
  }
  for (int e = threadIdx.x; e < 11 * 128; e += 512) {
    int d = e >> 7, p = e & 127;
    float t = 0.f;
#pragma unroll
    for (int w = 0; w < 8; ++w) t += S[w][d][p];
    int col = (p < 64) ? (2 * p) : (2 * (p - 64) + 1);   // de-permute
    Spart[(((size_t)s * 128 + m) * 11 + d) * 128 + col] = t;
  }
  if (threadIdx.x < 11) {
    int t = 0;
#pragma unroll
    for (int w = 0; w < 8; ++w) t += C[w][threadIdx.x];
    cntPart[((size_t)s * 128 + m) * 11 + threadIdx.x] = t;
  }
}

// ---------------------------------------------------------------------------
// K_ynfinal: yn = LN( sum_d S[m,d] @ Wg_d + cnt[m,d]*bg_d ) -> out1, and
// merge NSLICES max slices -> out2. 128 blocks x 128 threads.
// ---------------------------------------------------------------------------
__global__ __launch_bounds__(128) void k_ynfinal(
    const float* __restrict__ Spart,
    const int* __restrict__ cntPart,
    const float* __restrict__ W,
    const float* __restrict__ b,
    const float* __restrict__ gamma,
    const float* __restrict__ beta,
    const float* __restrict__ pmax4,        // [NSLICES][128][128]
    float* __restrict__ out1,
    float* __restrict__ out2)
{
  int m = blockIdx.x;
  int j = threadIdx.x;

  float g = __int_as_float((int)NEG_INF_BITS);
#pragma unroll
  for (int sl = 0; sl < NSLICES; ++sl)
    g = fmaxf(g, pmax4[((size_t)sl * 128 + m) * 128 + j]);
  out2[m * 128 + j] = g;

  __shared__ float Sm[11][128];
  __shared__ float cw[11];
  for (int e = j; e < 11 * 128; e += 128) {
    int d = e >> 7, c = e & 127;
    float t = 0.f;
#pragma unroll
    for (int sl = 0; sl < NSLICES; ++sl)
      t += Spart[(((size_t)sl * 128 + m) * 11 + d) * 128 + c];
    Sm[d][c] = t;
  }
  if (j < 11) {
    int t = 0;
#pragma unroll
    for (int sl = 0; sl < NSLICES; ++sl)
      t += cntPart[((size_t)sl * 128 + m) * 11 + j];
    cw[j] = (float)t;
  }
  __syncthreads();

  float acc = 0.f;
  for (int d = 0; d < 11; ++d) {
    int wi = (d >= 1) ? (20 + d) : 31;
    const float* Wd = W + wi * 16384;
    float a0 = 0.f, a1 = 0.f, a2 = 0.f, a3 = 0.f;
    for (int k = 0; k < 128; k += 4) {
      a0 += Sm[d][k]     * Wd[k * 128 + j];
      a1 += Sm[d][k + 1] * Wd[(k + 1) * 128 + j];
      a2 += Sm[d][k + 2] * Wd[(k + 2) * 128 + j];
      a3 += Sm[d][k + 3] * Wd[(k + 3) * 128 + j];
    }
    acc += (a0 + a1) + (a2 + a3);
    acc += cw[d] * b[wi * 128 + j];
  }

  float ws_ = acc, wq = acc * acc;
#pragma unroll
  for (int off = 32; off >= 1; off >>= 1) {
    ws_ += __shfl_xor(ws_, off, 64);
    wq  += __shfl_xor(wq, off, 64);
  }
  __shared__ float red[4];
  int wave = j >> 6, lane = j & 63;
  if (lane == 0) { red[wave * 2] = ws_; red[wave * 2 + 1] = wq; }
  __syncthreads();
  float Ssum = red[0] + red[2], Q = red[1] + red[3];
  float mean = Ssum * (1.f / 128.f);
  float var = Q * (1.f / 128.f) - mean * mean;
  float inv = 1.f / (sqrtf(var + 1e-5f) + 1e-5f);
  out1[m * 128 + j] = gamma[j] * ((acc - mean) * inv) + beta[j];
}

// ---------------------------------------------------------------------------
extern "C" void kernel_launch(void* const* d_in, const int* in_sizes, int n_in,
                              void* d_out, int out_size, void* d_ws, size_t ws_size,
                              hipStream_t stream) {
  const float* atoms = (const float*)d_in[0];
  // d_in[1] = deg_slice (unused; buckets are static)
  const int* membership = (const int*)d_in[2];
  AdjPtrs adj;
  for (int i = 0; i < 10; ++i) adj.p[i] = (const int*)d_in[3 + i];
  const float* W     = (const float*)d_in[13];
  const float* b     = (const float*)d_in[14];
  const float* gamma = (const float*)d_in[15];
  const float* beta  = (const float*)d_in[16];

  char* ws = (char*)d_ws;
  size_t off = 0;
  unsigned short* atomsBf = (unsigned short*)(ws + off); off += (size_t)N_ATOMS * 128 * 2;
  unsigned short* BcatT   = (unsigned short*)(ws + off); off += (size_t)11 * 128 * 256 * 2;
  float* biascat          = (float*)(ws + off);          off += (size_t)11 * 128 * 4;
  int* perm               = (int*)(ws + off);            off += (size_t)N_ATOMS * 4;
  int* tot                = (int*)(ws + off);            off += 512;
  int* blockHistT         = (int*)(ws + off);            off += (size_t)BATCH * SORT_BLOCKS * 4;
  int* relOffT            = (int*)(ws + off);            off += (size_t)BATCH * SORT_BLOCKS * 4;
  float* Spart            = (float*)(ws + off);          off += (size_t)NSLICES * 128 * 11 * 128 * 4;
  int* cntPart            = (int*)(ws + off);            off += (size_t)NSLICES * 128 * 11 * 4;
  float* pmax4            = (float*)(ws + off);          off += (size_t)NSLICES * 128 * 128 * 4;

  float* out0 = (float*)d_out;
  float* out1 = out0 + (size_t)N_ATOMS * 128;
  float* out2 = out1 + 16384;

  // 1) build B/bias + cast + histogram (block-range dispatch, one launch)
  hipLaunchKernelGGL(k_prep, dim3(NB_BUILD + NB_CAST + SORT_BLOCKS), dim3(256), 0, stream,
                     W, b, (const f32x4*)atoms, membership,
                     BcatT, biascat, (ushort4*)atomsBf, blockHistT);
  // 2) parallel scan -> relOffT + tot
  hipLaunchKernelGGL(k_scan, dim3(128), dim3(256), 0, stream, blockHistT, relOffT, tot);
  // 3) scatter -> perm
  hipLaunchKernelGGL(k_scatter, dim3(SORT_BLOCKS), dim3(256), 0, stream,
                     membership, relOffT, tot, perm);
  // 4) fused nsum (4-row MLP) + activated GEMM + LN (1D round-robin grid)
  hipLaunchKernelGGL(k_gemm, dim3(236 * 11), dim3(512), 0, stream,
                     atomsBf, adj, BcatT, biascat, gamma, beta, out0);
  // 5) fused segment-max(xn) + per-(mol,deg) atom sums (4-row MLP)
  hipLaunchKernelGGL(k_mreduce, dim3(128 * NSLICES), dim3(512), 0, stream,
                     (const f32x2*)out0, (const unsigned*)atomsBf, perm, tot,
                     Spart, cntPart, (float2*)pmax4);
  // 6) yn (algebraic gathered path) + max merge
  hipLaunchKernelGGL(k_ynfinal, dim3(128), dim3(128), 0, stream,
                     Spart, cntPart, W, b, gamma, beta, pmax4, out1, out2);
}